// Round 4
// baseline (220.746 us; speedup 1.0000x reference)
//
#include <hip/hip_runtime.h>
#include <stdint.h>

// VectorQuantizer on MI355X — round 3: conflict-free chunk-planar staging.
// latent [32,256,1024] fp32, codebook [1024,256] fp32.
// d_out float regions: Xt bf16 [0,4194304) | Ebf bf16 [4194304,4325376)
// | e2 [4325376,4326400) — consumed by k_argmin, overwritten by k_out's q_st.
// ws = packed u64[32768]: atomicMin of {monotone_score_key:32 | k:32}.

#define D_   256
#define HW_  1024
#define N_   32768
#define K_   1024

typedef __attribute__((ext_vector_type(8))) short  s8v;   // 8 bf16 (4 VGPR)
typedef __attribute__((ext_vector_type(4))) float  f4v;   // MFMA acc

__device__ __forceinline__ ushort bf16rne(float x) {
  unsigned u = __float_as_uint(x);
  return (ushort)((u + 0x7FFFu + ((u >> 16) & 1u)) >> 16);
}

// monotone map: unsigned order of key == float order (handles negatives)
__device__ __forceinline__ unsigned fkey(float f) {
  unsigned u = __float_as_uint(f);
  return u ^ (unsigned)(((int)u >> 31) | 0x80000000);
}

// async global->LDS DMA, 16 B/lane; LDS dest = wave-uniform base + lane*16
__device__ __forceinline__ void gld_lds16(const void* g, void* l) {
  __builtin_amdgcn_global_load_lds(
      (const __attribute__((address_space(1))) unsigned int*)g,
      (__attribute__((address_space(3))) unsigned int*)l, 16, 0, 0);
}

// ---------- codebook -> bf16 chunk-planar [dq(32)][code(1024)][8] + e2 ----------
__global__ __launch_bounds__(256) void k_eprep(const float* __restrict__ cb,
                                               ushort* __restrict__ Ebf,
                                               float* __restrict__ e2,
                                               float* __restrict__ loss) {
  const int t = threadIdx.x, blk = blockIdx.x;   // 64 blocks x 16 codes
  if (blk == 0 && t == 0) *loss = 0.f;
#pragma unroll
  for (int it = 0; it < 2; ++it) {
    int c = it * 256 + t;                        // 512 chunks/block
    int cl = c & 15, dq = c >> 4;                // code-local, d-chunk
    const float* src = cb + (size_t)(blk * 16 + cl) * 256 + dq * 8;
    float4 v0 = ((const float4*)src)[0], v1 = ((const float4*)src)[1];
    ushort tmp[8] __attribute__((aligned(16)));
    tmp[0] = bf16rne(v0.x); tmp[1] = bf16rne(v0.y);
    tmp[2] = bf16rne(v0.z); tmp[3] = bf16rne(v0.w);
    tmp[4] = bf16rne(v1.x); tmp[5] = bf16rne(v1.y);
    tmp[6] = bf16rne(v1.z); tmp[7] = bf16rne(v1.w);
    *(uint4*)(Ebf + ((size_t)dq * 1024 + blk * 16 + cl) * 8) = *(uint4*)tmp;
  }
  // e2 numpy-pairwise: 16 lanes/row, butterfly reproduces pairwise tree
  const int row = blk * 16 + (t >> 4);
  const int sub = t & 15, j = sub & 7, h = sub >> 3;
  const float* base = cb + row * 256 + h * 128 + j;
  float r = __fmul_rn(base[0], base[0]);
  for (int i = 1; i < 16; ++i) {
    float v = base[8 * i];
    r = __fadd_rn(r, __fmul_rn(v, v));
  }
#pragma unroll
  for (int m = 1; m < 16; m <<= 1) r = __fadd_rn(r, __shfl_xor(r, m, 64));
  if (sub == 0) e2[row] = r;
}

// ---------- latent -> bf16 chunk-planar [tile(256)][dq(32)][pos(128)][8] ----------
__global__ __launch_bounds__(256) void k_xprep(const float* __restrict__ latent,
                                               ushort* __restrict__ Xt,
                                               unsigned long long* __restrict__ packed) {
  __shared__ float Xf[64 * 132];                 // 33 KB, pitch 132 (16B-aligned)
  const int t = threadIdx.x, tile = blockIdx.x;  // 256 tiles x 128 pos
  int gid = tile * 256 + t;
  if (gid < N_) packed[gid] = ~0ull;             // init argmin keys
  const int b = tile >> 3, hw0 = (tile & 7) * 128;
  const float* Lb = latent + (size_t)b * (D_ * HW_) + hw0;
  for (int s = 0; s < 4; ++s) {                  // 4 slabs of 64 d
    __syncthreads();
#pragma unroll
    for (int it = 0; it < 8; ++it) {             // load [64 d][128 hw] fp32
      int idx = it * 256 + t;
      int d = idx >> 5, hq = idx & 31;
      float4 v = *(const float4*)(Lb + (size_t)(s * 64 + d) * HW_ + hq * 4);
      *(float4*)&Xf[d * 132 + hq * 4] = v;
    }
    __syncthreads();
#pragma unroll
    for (int it = 0; it < 4; ++it) {             // transpose-convert out
      int idx = it * 256 + t;
      int pos = idx & 127, dq = idx >> 7;        // dq 0..7 within slab
      ushort tmp[8] __attribute__((aligned(16)));
#pragma unroll
      for (int e = 0; e < 8; ++e) tmp[e] = bf16rne(Xf[(dq * 8 + e) * 132 + pos]);
      *(uint4*)(Xt + ((size_t)(tile * 32 + s * 8 + dq) * 128 + pos) * 8) =
          *(uint4*)tmp;
    }
  }
}

// ---------- MFMA distance GEMM + argmin ----------
// Grid 512 = 256 pos-tiles (128) x 2 k-splits (512 codes). Block 256 = 4
// waves, each wave-tile 128 pos x 128 codes (8mi x 8kj of 16x16x32, acc 64
// VGPR). Chunk-planar LDS: every frag read = 16 contiguous 16B lanes
// (conflict-free); DMA source lane-contiguous. Score = e2 - 2*dot (x2 is a
// per-position constant, argmin-invariant); merge via atomicMin on
// {fkey(score):32 | k:32}; first-min tie-break via low bits.
__global__ __launch_bounds__(256, 2) void k_argmin(
    const ushort* __restrict__ Xt, const ushort* __restrict__ Ebf,
    const float* __restrict__ e2g, unsigned long long* __restrict__ packed) {
  __shared__ alignas(16) ushort Xs[128 * 32];    // [q(4)][pos(128)][8]  8 KB
  __shared__ alignas(16) ushort Es[512 * 32];    // [q(4)][code(512)][8] 32 KB
  __shared__ float e2s[512];
  const int t = threadIdx.x;
  const int split = blockIdx.x & 1, tile = blockIdx.x >> 1;
  const int k0 = split * 512;
  const int lane = t & 63, w = t >> 6;
  const int lrow = lane & 15, q = lane >> 4;

  e2s[t] = e2g[k0 + t];
  e2s[t + 256] = e2g[k0 + 256 + t];

  f4v acc[8][8];
#pragma unroll
  for (int mi = 0; mi < 8; ++mi)
#pragma unroll
    for (int kj = 0; kj < 8; ++kj) acc[mi][kj] = (f4v){0.f, 0.f, 0.f, 0.f};

  const ushort* Xg = Xt + (size_t)tile * 32768;  // 32 dq x 128 pos x 8

  for (int ch = 0; ch < 8; ++ch) {               // 8 chunks of 32 d
    __syncthreads();                             // prev chunk consumed
#pragma unroll
    for (int ii = 0; ii < 2; ++ii) {             // X: 8 insts, 2/wave
      int j = w * 2 + ii;
      gld_lds16(Xg + ((size_t)(ch * 4 + (j >> 1)) * 128 + (j & 1) * 64 + lane) * 8,
                &Xs[(j * 64 + lane) * 8]);
    }
#pragma unroll
    for (int ii = 0; ii < 8; ++ii) {             // E: 32 insts, 8/wave
      int j = w * 8 + ii;
      gld_lds16(Ebf + ((size_t)(ch * 4 + (j >> 3)) * 1024 + k0 + (j & 7) * 64 + lane) * 8,
                &Es[(j * 64 + lane) * 8]);
    }
    __syncthreads();                             // drains DMA (vmcnt)
    s8v a_[8];
#pragma unroll
    for (int mi = 0; mi < 8; ++mi)
      a_[mi] = *(const s8v*)&Xs[((size_t)q * 128 + mi * 16 + lrow) * 8];
#pragma unroll
    for (int kj = 0; kj < 8; ++kj) {
      s8v b_ = *(const s8v*)&Es[((size_t)q * 512 + w * 128 + kj * 16 + lrow) * 8];
#pragma unroll
      for (int mi = 0; mi < 8; ++mi)
        acc[mi][kj] = __builtin_amdgcn_mfma_f32_16x16x32_bf16(
            a_[mi], b_, acc[mi][kj], 0, 0, 0);
    }
  }

  float e2v[8];
#pragma unroll
  for (int kj = 0; kj < 8; ++kj) e2v[kj] = e2s[w * 128 + kj * 16 + lrow];
#pragma unroll
  for (int mi = 0; mi < 8; ++mi) {
#pragma unroll
    for (int reg = 0; reg < 4; ++reg) {
      float best = 3.4e38f;
      int bk = 0;
#pragma unroll
      for (int kj = 0; kj < 8; ++kj) {           // kj ascending: first-min
        float s = __fadd_rn(e2v[kj], -2.f * acc[mi][kj][reg]);
        if (s < best) { best = s; bk = k0 + w * 128 + kj * 16 + lrow; }
      }
#pragma unroll
      for (int m = 1; m < 16; m <<= 1) {         // reduce over lrow
        float ob = __shfl_xor(best, m, 64);
        int ok = __shfl_xor(bk, m, 64);
        if (ob < best || (ob == best && ok < bk)) { best = ob; bk = ok; }
      }
      if (lrow == 0) {
        int p = tile * 128 + mi * 16 + q * 4 + reg;
        atomicMin(&packed[p],
                  ((unsigned long long)fkey(best) << 32) | (unsigned)bk);
      }
    }
  }
}

// ---------- gather + straight-through output + loss ----------
// Thread owns (pos-quad, 16 d): cb gathered as float4 over d (L2-resident),
// x/out as contiguous float4 over hw. 48 VMEM insts/thread.
__global__ __launch_bounds__(256) void k_out(
    const float* __restrict__ latent, const float* __restrict__ cb,
    const unsigned long long* __restrict__ packed, float* __restrict__ out,
    float* __restrict__ loss) {
  __shared__ float red[4];
  const int gid = blockIdx.x * 256 + threadIdx.x;  // 131072
  const int pq = gid & 8191, dgg = gid >> 13;      // 16 d-groups of 16 d
  const int b = pq >> 8, hwq = pq & 255;
  const unsigned long long* pp = packed + (size_t)b * 1024 + hwq * 4;
  int idx[4];
#pragma unroll
  for (int e = 0; e < 4; ++e) idx[e] = (int)(unsigned)(pp[e] & 0xFFFFFFFFull);
  const float* Lb = latent + (size_t)b * (D_ * HW_) + hwq * 4;
  float* Ob = out + (size_t)b * (D_ * HW_) + hwq * 4;
  float part = 0.f;
#pragma unroll
  for (int j = 0; j < 4; ++j) {
    int d0 = dgg * 16 + j * 4;
    float ce[4][4] __attribute__((aligned(16)));   // [pos e][d r]
#pragma unroll
    for (int e = 0; e < 4; ++e)
      *(float4*)ce[e] = *(const float4*)(cb + (size_t)idx[e] * 256 + d0);
#pragma unroll
    for (int r = 0; r < 4; ++r) {
      float4 x = *(const float4*)(Lb + (size_t)(d0 + r) * HW_);
      float4 o;
      float df;
      df = __fsub_rn(ce[0][r], x.x); o.x = __fadd_rn(x.x, df); part = fmaf(df, df, part);
      df = __fsub_rn(ce[1][r], x.y); o.y = __fadd_rn(x.y, df); part = fmaf(df, df, part);
      df = __fsub_rn(ce[2][r], x.z); o.z = __fadd_rn(x.z, df); part = fmaf(df, df, part);
      df = __fsub_rn(ce[3][r], x.w); o.w = __fadd_rn(x.w, df); part = fmaf(df, df, part);
      *(float4*)(Ob + (size_t)(d0 + r) * HW_) = o;   // x + (q - x), NOT q
    }
  }
#pragma unroll
  for (int off = 32; off > 0; off >>= 1) part += __shfl_down(part, off, 64);
  if ((threadIdx.x & 63) == 0) red[threadIdx.x >> 6] = part;
  __syncthreads();
  if (threadIdx.x == 0)
    atomicAdd(loss, (red[0] + red[1] + red[2] + red[3]) * (1.25f / 8388608.0f));
}

extern "C" void kernel_launch(void* const* d_in, const int* in_sizes, int n_in,
                              void* d_out, int out_size, void* d_ws, size_t ws_size,
                              hipStream_t stream) {
  const float* latent = (const float*)d_in[0];
  const float* cb     = (const float*)d_in[1];
  float* out  = (float*)d_out;
  float* loss = out + (size_t)N_ * D_;             // element 8,388,608
  ushort* Xt  = (ushort*)out;                      // floats [0, 4194304)
  ushort* Ebf = (ushort*)(out + 4194304);          // floats [4194304, 4325376)
  float*  e2  = out + 4325376;                     // 1024 floats
  unsigned long long* packed = (unsigned long long*)d_ws;

  hipLaunchKernelGGL(k_eprep,  dim3(64),  dim3(256), 0, stream, cb, Ebf, e2, loss);
  hipLaunchKernelGGL(k_xprep,  dim3(256), dim3(256), 0, stream, latent, Xt, packed);
  hipLaunchKernelGGL(k_argmin, dim3(512), dim3(256), 0, stream, Xt, Ebf, e2, packed);
  hipLaunchKernelGGL(k_out,    dim3(512), dim3(256), 0, stream, latent, cb, packed, out, loss);
}

// Round 5
// 139.672 us; speedup vs baseline: 1.5805x; 1.5805x over previous
//
#include <hip/hip_runtime.h>
#include <stdint.h>

// VectorQuantizer on MI355X — round 4: chunk-planar conflict-free staging,
// spill-free wave tile (64 pos x 128 codes, acc[4][8] = 128 regs).
// latent [32,256,1024] fp32, codebook [1024,256] fp32.
// d_out float regions: Xt bf16 [0,4194304) | Ebf bf16 [4194304,4325376)
// | e2 [4325376,4326400) — consumed by k_argmin, overwritten by k_out's q_st.
// ws = packed u64[32768]: atomicMin of {monotone_score_key:32 | k:32}.

#define D_   256
#define HW_  1024
#define N_   32768
#define K_   1024

typedef __attribute__((ext_vector_type(8))) short  s8v;   // 8 bf16 (4 VGPR)
typedef __attribute__((ext_vector_type(4))) float  f4v;   // MFMA acc

__device__ __forceinline__ ushort bf16rne(float x) {
  unsigned u = __float_as_uint(x);
  return (ushort)((u + 0x7FFFu + ((u >> 16) & 1u)) >> 16);
}

// monotone map: unsigned order of key == float order (handles negatives)
__device__ __forceinline__ unsigned fkey(float f) {
  unsigned u = __float_as_uint(f);
  return u ^ (unsigned)(((int)u >> 31) | 0x80000000);
}

// async global->LDS DMA, 16 B/lane; LDS dest = wave-uniform base + lane*16
__device__ __forceinline__ void gld_lds16(const void* g, void* l) {
  __builtin_amdgcn_global_load_lds(
      (const __attribute__((address_space(1))) unsigned int*)g,
      (__attribute__((address_space(3))) unsigned int*)l, 16, 0, 0);
}

// ---------- codebook -> bf16 chunk-planar [dq(32)][code(1024)][8] + e2 ----------
__global__ __launch_bounds__(256) void k_eprep(const float* __restrict__ cb,
                                               ushort* __restrict__ Ebf,
                                               float* __restrict__ e2,
                                               float* __restrict__ loss) {
  const int t = threadIdx.x, blk = blockIdx.x;   // 64 blocks x 16 codes
  if (blk == 0 && t == 0) *loss = 0.f;
#pragma unroll
  for (int it = 0; it < 2; ++it) {
    int c = it * 256 + t;                        // 512 chunks/block
    int cl = c & 15, dq = c >> 4;                // code-local, d-chunk
    const float* src = cb + (size_t)(blk * 16 + cl) * 256 + dq * 8;
    float4 v0 = ((const float4*)src)[0], v1 = ((const float4*)src)[1];
    ushort tmp[8] __attribute__((aligned(16)));
    tmp[0] = bf16rne(v0.x); tmp[1] = bf16rne(v0.y);
    tmp[2] = bf16rne(v0.z); tmp[3] = bf16rne(v0.w);
    tmp[4] = bf16rne(v1.x); tmp[5] = bf16rne(v1.y);
    tmp[6] = bf16rne(v1.z); tmp[7] = bf16rne(v1.w);
    *(uint4*)(Ebf + ((size_t)dq * 1024 + blk * 16 + cl) * 8) = *(uint4*)tmp;
  }
  // e2 numpy-pairwise: 16 lanes/row, butterfly reproduces pairwise tree
  const int row = blk * 16 + (t >> 4);
  const int sub = t & 15, j = sub & 7, h = sub >> 3;
  const float* base = cb + row * 256 + h * 128 + j;
  float r = __fmul_rn(base[0], base[0]);
  for (int i = 1; i < 16; ++i) {
    float v = base[8 * i];
    r = __fadd_rn(r, __fmul_rn(v, v));
  }
#pragma unroll
  for (int m = 1; m < 16; m <<= 1) r = __fadd_rn(r, __shfl_xor(r, m, 64));
  if (sub == 0) e2[row] = r;
}

// ---------- latent -> bf16 chunk-planar [tile(256)][dq(32)][pos(128)][8] ----------
__global__ __launch_bounds__(256) void k_xprep(const float* __restrict__ latent,
                                               ushort* __restrict__ Xt,
                                               unsigned long long* __restrict__ packed) {
  __shared__ float Xf[64 * 132];                 // 33 KB, pitch 132 (16B-aligned)
  const int t = threadIdx.x, tile = blockIdx.x;  // 256 tiles x 128 pos
  int gid = tile * 256 + t;
  if (gid < N_) packed[gid] = ~0ull;             // init argmin keys
  const int b = tile >> 3, hw0 = (tile & 7) * 128;
  const float* Lb = latent + (size_t)b * (D_ * HW_) + hw0;
  for (int s = 0; s < 4; ++s) {                  // 4 slabs of 64 d
    __syncthreads();
#pragma unroll
    for (int it = 0; it < 8; ++it) {             // load [64 d][128 hw] fp32
      int idx = it * 256 + t;
      int d = idx >> 5, hq = idx & 31;
      float4 v = *(const float4*)(Lb + (size_t)(s * 64 + d) * HW_ + hq * 4);
      *(float4*)&Xf[d * 132 + hq * 4] = v;
    }
    __syncthreads();
#pragma unroll
    for (int it = 0; it < 4; ++it) {             // transpose-convert out
      int idx = it * 256 + t;
      int pos = idx & 127, dq = idx >> 7;        // dq 0..7 within slab
      ushort tmp[8] __attribute__((aligned(16)));
#pragma unroll
      for (int e = 0; e < 8; ++e) tmp[e] = bf16rne(Xf[(dq * 8 + e) * 132 + pos]);
      *(uint4*)(Xt + ((size_t)(tile * 32 + s * 8 + dq) * 128 + pos) * 8) =
          *(uint4*)tmp;
    }
  }
}

// ---------- MFMA distance GEMM + argmin ----------
// Grid 1024 = 256 pos-tiles (128) x 4 k-splits (256 codes). Block 256 = 4
// waves (wm x wk), wave tile 64 pos x 128 codes = 4mi x 8kj of 16x16x32,
// acc[4][8] = 128 regs (+~50 aux) < 256 cap of launch_bounds(256,2): NO
// spills (round-3 lesson). Chunk-planar LDS: DMA lane-contiguous, every frag
// read = 16 contiguous 16B lanes (2-way, free). Score = e2 - 2*dot (x2 is
// argmin-invariant); merge via atomicMin{fkey(score):32 | k:32}.
__global__ __launch_bounds__(256, 2) void k_argmin(
    const ushort* __restrict__ Xt, const ushort* __restrict__ Ebf,
    const float* __restrict__ e2g, unsigned long long* __restrict__ packed) {
  __shared__ alignas(16) ushort Xs[8 * 128 * 8];   // [dqL][pos][8]  16 KB
  __shared__ alignas(16) ushort Es[8 * 256 * 8];   // [dqL][code][8] 32 KB
  __shared__ float e2s[256];
  const int t = threadIdx.x;
  const int split = blockIdx.x & 3, tile = blockIdx.x >> 2;
  const int k0 = split * 256;
  const int lane = t & 63, w = t >> 6;
  const int wm = w >> 1, wk = w & 1;
  const int lrow = lane & 15, q = lane >> 4;

  e2s[t] = e2g[k0 + t];

  f4v acc[4][8];
#pragma unroll
  for (int mi = 0; mi < 4; ++mi)
#pragma unroll
    for (int kj = 0; kj < 8; ++kj) acc[mi][kj] = (f4v){0.f, 0.f, 0.f, 0.f};

  const ushort* Xg = Xt + (size_t)tile * 32768;  // 32 dq x 128 pos x 8

  for (int ch = 0; ch < 4; ++ch) {               // 4 chunks of 64 d
    __syncthreads();                             // prev chunk consumed
#pragma unroll
    for (int ii = 0; ii < 4; ++ii) {             // X: 16 KB, 16 insts, 4/wave
      int j = w * 4 + ii;                        // dqL = j>>1, half = j&1
      gld_lds16(Xg + ((size_t)(ch * 8 + (j >> 1)) * 128 + (j & 1) * 64 + lane) * 8,
                &Xs[(((j >> 1) * 128) + (j & 1) * 64 + lane) * 8]);
    }
#pragma unroll
    for (int ii = 0; ii < 8; ++ii) {             // E: 32 KB, 32 insts, 8/wave
      int j = w * 8 + ii;                        // dqL = j>>2, quarter = j&3
      gld_lds16(Ebf + ((size_t)(ch * 8 + (j >> 2)) * 1024 + k0 + (j & 3) * 64 + lane) * 8,
                &Es[(((j >> 2) * 256) + (j & 3) * 64 + lane) * 8]);
    }
    __syncthreads();                             // drains DMA (vmcnt)
#pragma unroll
    for (int s = 0; s < 2; ++s) {                // 2 K-steps of 32 d
      s8v a_[4];
#pragma unroll
      for (int mi = 0; mi < 4; ++mi)
        a_[mi] = *(const s8v*)
            &Xs[((size_t)(s * 4 + q) * 128 + wm * 64 + mi * 16 + lrow) * 8];
#pragma unroll
      for (int kj = 0; kj < 8; ++kj) {
        s8v b_ = *(const s8v*)
            &Es[((size_t)(s * 4 + q) * 256 + wk * 128 + kj * 16 + lrow) * 8];
#pragma unroll
        for (int mi = 0; mi < 4; ++mi)
          acc[mi][kj] = __builtin_amdgcn_mfma_f32_16x16x32_bf16(
              a_[mi], b_, acc[mi][kj], 0, 0, 0);
      }
    }
  }

  float e2v[8];
#pragma unroll
  for (int kj = 0; kj < 8; ++kj) e2v[kj] = e2s[wk * 128 + kj * 16 + lrow];
#pragma unroll
  for (int mi = 0; mi < 4; ++mi) {
#pragma unroll
    for (int reg = 0; reg < 4; ++reg) {
      float best = 3.4e38f;
      int bk = 0;
#pragma unroll
      for (int kj = 0; kj < 8; ++kj) {           // kj ascending: first-min
        float s = __fadd_rn(e2v[kj], -2.f * acc[mi][kj][reg]);
        if (s < best) { best = s; bk = k0 + wk * 128 + kj * 16 + lrow; }
      }
#pragma unroll
      for (int m = 1; m < 16; m <<= 1) {         // reduce over lrow
        float ob = __shfl_xor(best, m, 64);
        int ok = __shfl_xor(bk, m, 64);
        if (ob < best || (ob == best && ok < bk)) { best = ob; bk = ok; }
      }
      if (lrow == 0) {
        int p = tile * 128 + wm * 64 + mi * 16 + q * 4 + reg;
        atomicMin(&packed[p],
                  ((unsigned long long)fkey(best) << 32) | (unsigned)bk);
      }
    }
  }
}

// ---------- gather + straight-through output + loss ----------
// Thread owns (pos-quad, 16 d): cb gathered as float4 over d (L2-resident),
// x/out as contiguous float4 over hw.
__global__ __launch_bounds__(256) void k_out(
    const float* __restrict__ latent, const float* __restrict__ cb,
    const unsigned long long* __restrict__ packed, float* __restrict__ out,
    float* __restrict__ loss) {
  __shared__ float red[4];
  const int gid = blockIdx.x * 256 + threadIdx.x;  // 131072
  const int pq = gid & 8191, dgg = gid >> 13;      // 16 d-groups of 16 d
  const int b = pq >> 8, hwq = pq & 255;
  const unsigned long long* pp = packed + (size_t)b * 1024 + hwq * 4;
  int idx[4];
#pragma unroll
  for (int e = 0; e < 4; ++e) idx[e] = (int)(unsigned)(pp[e] & 0xFFFFFFFFull);
  const float* Lb = latent + (size_t)b * (D_ * HW_) + hwq * 4;
  float* Ob = out + (size_t)b * (D_ * HW_) + hwq * 4;
  float part = 0.f;
#pragma unroll
  for (int j = 0; j < 4; ++j) {
    int d0 = dgg * 16 + j * 4;
    float ce[4][4] __attribute__((aligned(16)));   // [pos e][d r]
#pragma unroll
    for (int e = 0; e < 4; ++e)
      *(float4*)ce[e] = *(const float4*)(cb + (size_t)idx[e] * 256 + d0);
#pragma unroll
    for (int r = 0; r < 4; ++r) {
      float4 x = *(const float4*)(Lb + (size_t)(d0 + r) * HW_);
      float4 o;
      float df;
      df = __fsub_rn(ce[0][r], x.x); o.x = __fadd_rn(x.x, df); part = fmaf(df, df, part);
      df = __fsub_rn(ce[1][r], x.y); o.y = __fadd_rn(x.y, df); part = fmaf(df, df, part);
      df = __fsub_rn(ce[2][r], x.z); o.z = __fadd_rn(x.z, df); part = fmaf(df, df, part);
      df = __fsub_rn(ce[3][r], x.w); o.w = __fadd_rn(x.w, df); part = fmaf(df, df, part);
      *(float4*)(Ob + (size_t)(d0 + r) * HW_) = o;   // x + (q - x), NOT q
    }
  }
#pragma unroll
  for (int off = 32; off > 0; off >>= 1) part += __shfl_down(part, off, 64);
  if ((threadIdx.x & 63) == 0) red[threadIdx.x >> 6] = part;
  __syncthreads();
  if (threadIdx.x == 0)
    atomicAdd(loss, (red[0] + red[1] + red[2] + red[3]) * (1.25f / 8388608.0f));
}

extern "C" void kernel_launch(void* const* d_in, const int* in_sizes, int n_in,
                              void* d_out, int out_size, void* d_ws, size_t ws_size,
                              hipStream_t stream) {
  const float* latent = (const float*)d_in[0];
  const float* cb     = (const float*)d_in[1];
  float* out  = (float*)d_out;
  float* loss = out + (size_t)N_ * D_;             // element 8,388,608
  ushort* Xt  = (ushort*)out;                      // floats [0, 4194304)
  ushort* Ebf = (ushort*)(out + 4194304);          // floats [4194304, 4325376)
  float*  e2  = out + 4325376;                     // 1024 floats
  unsigned long long* packed = (unsigned long long*)d_ws;

  hipLaunchKernelGGL(k_eprep,  dim3(64),   dim3(256), 0, stream, cb, Ebf, e2, loss);
  hipLaunchKernelGGL(k_xprep,  dim3(256),  dim3(256), 0, stream, latent, Xt, packed);
  hipLaunchKernelGGL(k_argmin, dim3(1024), dim3(256), 0, stream, Xt, Ebf, e2, packed);
  hipLaunchKernelGGL(k_out,    dim3(512),  dim3(256), 0, stream, latent, cb, packed, out, loss);
}